// Round 1
// baseline (140.620 us; speedup 1.0000x reference)
//
#include <hip/hip_runtime.h>
#include <stdint.h>

typedef short short8 __attribute__((ext_vector_type(8)));
typedef float f32x4 __attribute__((ext_vector_type(4)));

#define AS1 __attribute__((address_space(1)))
#define AS3 __attribute__((address_space(3)))

__device__ __forceinline__ void gl_lds16(const void* g, void* l) {
  __builtin_amdgcn_global_load_lds((const AS1 unsigned int*)g,
                                   (AS3 unsigned int*)l, 16, 0, 0);
}

__device__ __forceinline__ unsigned short f2bf(float f) {
  union { float f; unsigned int u; } v; v.f = f;
  // round-to-nearest-even bf16
  return (unsigned short)((v.u + (((v.u >> 16) & 1u) + 0x7fffu)) >> 16);
}

// ---------------------------------------------------------------------------
// Pre-pass 1: x [16][256][64][64] fp32 NCHW  ->  x_t [16][64][64][256] bf16 NHWC
// Block handles (b, y, ci-chunk of 64). LDS transpose, coalesced both sides.
// ---------------------------------------------------------------------------
__global__ __launch_bounds__(256) void xpose_kernel(const float* __restrict__ x,
                                                    unsigned short* __restrict__ xt) {
  __shared__ float tile[64][68];  // +4 pad: 16B-aligned rows, conflict-light
  const int bid = blockIdx.x;
  const int cchunk = bid & 3;          // 4 chunks of 64 ci
  const int y = (bid >> 2) & 63;
  const int b = bid >> 8;              // 16
  const int t = threadIdx.x;
  const int ci0 = cchunk * 64;

  // load: thread t -> ci row (t>>2), 16 contiguous x positions
  const int cc = t >> 2;
  const int xo = (t & 3) * 16;
  const float* src = x + (((size_t)(b * 256 + ci0 + cc) * 64 + y) * 64 + xo);
  float4 v0 = ((const float4*)src)[0];
  float4 v1 = ((const float4*)src)[1];
  float4 v2 = ((const float4*)src)[2];
  float4 v3 = ((const float4*)src)[3];
  *(float4*)&tile[cc][xo + 0]  = v0;
  *(float4*)&tile[cc][xo + 4]  = v1;
  *(float4*)&tile[cc][xo + 8]  = v2;
  *(float4*)&tile[cc][xo + 12] = v3;
  __syncthreads();

  // store: thread t -> x position (t>>2), 16 contiguous ci (bf16)
  const int xpos = t >> 2;
  const int ccg = (t & 3) * 16;
  unsigned int pk[8];
#pragma unroll
  for (int e = 0; e < 8; ++e) {
    unsigned int lo = f2bf(tile[ccg + 2 * e][xpos]);
    unsigned int hi = f2bf(tile[ccg + 2 * e + 1][xpos]);
    pk[e] = lo | (hi << 16);
  }
  unsigned short* dst = xt + ((size_t)(b * 4096 + y * 64 + xpos) * 256 + ci0 + ccg);
  uint4 w0; w0.x = pk[0]; w0.y = pk[1]; w0.z = pk[2]; w0.w = pk[3];
  uint4 w1; w1.x = pk[4]; w1.y = pk[5]; w1.z = pk[6]; w1.w = pk[7];
  ((uint4*)dst)[0] = w0;
  ((uint4*)dst)[1] = w1;
}

// ---------------------------------------------------------------------------
// Pre-pass 2: w [256co][256ci][3][3] fp32 -> w_r [9 tap][256co][256ci] bf16
// ---------------------------------------------------------------------------
__global__ __launch_bounds__(256) void wpack_kernel(const float* __restrict__ w,
                                                    unsigned short* __restrict__ wrp) {
  const int idx = blockIdx.x * 256 + threadIdx.x;   // 9*256*256 = 589824 exactly
  const int ci = idx & 255;
  const int co = (idx >> 8) & 255;
  const int p = idx >> 16;
  wrp[idx] = f2bf(w[(size_t)(co * 256 + ci) * 9 + p]);
}

// ---------------------------------------------------------------------------
// Main: implicit-GEMM conv, 128co x 128px tiles, 16x16x32 bf16 MFMA,
// m97-style single-buffered LDS + global_load_lds(16B) staging.
// K-loop: 72 steps = 9 taps (outer) x 8 ci-chunks of 32 (inner).
// ---------------------------------------------------------------------------
__global__ __launch_bounds__(256) void conv_mfma(const unsigned short* __restrict__ xt,
                                                 const unsigned short* __restrict__ wrp,
                                                 const float* __restrict__ bias,
                                                 float* __restrict__ out) {
  __shared__ unsigned short Asm[128 * 32];  // [co][ci]
  __shared__ unsigned short Bsm[128 * 32];  // [px][ci]

  const int bid = blockIdx.x;
  const int co_t = bid & 1;               // co tile inner -> both share x in L2
  const int pt = bid >> 1;                // 496 pixel tiles
  const int b = pt / 31;
  const int oh0 = (pt - b * 31) * 2;      // 2 output rows per tile
  const int tid = threadIdx.x;
  const int lane = tid & 63;
  const int wv = tid >> 6;
  const int wrow = wv >> 1;               // wave co quadrant (0..1)
  const int wcol = wv & 1;                // wave px quadrant (0..1)
  const int co0 = co_t * 128;

  // --- staging lane-static offsets (elements) ---
  const int sub = lane >> 2;              // 0..15
  const int cio = (lane & 3) * 8;         // ci sub-offset
  size_t Astat[2], Bstat[2];
  unsigned ldsoff[2];
#pragma unroll
  for (int i = 0; i < 2; ++i) {
    const int row = wv * 32 + i * 16 + sub;     // tile-local row 0..127
    Astat[i] = (size_t)(co0 + row) * 256 + cio;
    const int prow = row >> 6;                  // 0..1 output row
    const int pcol = row & 63;                  // output col (62,63 = pad)
    Bstat[i] = (size_t)((b * 64 + oh0 + prow) * 64 + pcol) * 256 + cio;
    ldsoff[i] = wv * 1024 + i * 512;            // ushort elements
  }

  // --- fragment lane offsets ---
  const int frow = lane & 15;
  const int fk = (lane >> 4) * 8;

  f32x4 acc[4][4] = {};

  for (int kc = 0; kc < 72; ++kc) {
    const int p = kc >> 3;                // tap 0..8
    const int ci0 = (kc & 7) * 32;        // ci chunk
    const int kh = (p * 11) >> 5;         // p/3 for p<9
    const int kw = p - kh * 3;
    const int Aoff = p * 65536 + ci0;
    const int Boff = (kh * 64 + kw) * 256 + ci0;  // shift within NHWC image
#pragma unroll
    for (int i = 0; i < 2; ++i) {
      gl_lds16(wrp + Astat[i] + Aoff, Asm + ldsoff[i]);
      gl_lds16(xt + Bstat[i] + Boff, Bsm + ldsoff[i]);
    }
    __syncthreads();
    short8 a[4], bb[4];
#pragma unroll
    for (int m = 0; m < 4; ++m)
      a[m] = *(const short8*)(Asm + (wrow * 64 + m * 16 + frow) * 32 + fk);
#pragma unroll
    for (int n = 0; n < 4; ++n)
      bb[n] = *(const short8*)(Bsm + (wcol * 64 + n * 16 + frow) * 32 + fk);
#pragma unroll
    for (int m = 0; m < 4; ++m)
#pragma unroll
      for (int n = 0; n < 4; ++n)
        acc[m][n] = __builtin_amdgcn_mfma_f32_16x16x32_bf16(a[m], bb[n], acc[m][n], 0, 0, 0);
    __syncthreads();
  }

  // --- epilogue: D col=lane&15 -> px (coalesced), row=(lane>>4)*4+j -> co ---
  const int rbase = (lane >> 4) * 4;
  float bv[4][4];
#pragma unroll
  for (int m = 0; m < 4; ++m)
#pragma unroll
    for (int j = 0; j < 4; ++j)
      bv[m][j] = bias[co0 + wrow * 64 + m * 16 + rbase + j];
#pragma unroll
  for (int m = 0; m < 4; ++m) {
#pragma unroll
    for (int n = 0; n < 4; ++n) {
      const int px = wcol * 64 + n * 16 + (lane & 15);
      const int prow = px >> 6, ow = px & 63;
      if (ow < 62) {
#pragma unroll
        for (int j = 0; j < 4; ++j) {
          const int co = co0 + wrow * 64 + m * 16 + rbase + j;
          out[(size_t)(b * 256 + co) * 3844 + (size_t)(oh0 + prow) * 62 + ow] =
              acc[m][n][j] + bv[m][j];
        }
      }
    }
  }
}

// ---------------------------------------------------------------------------
// Fallback: naive fp32 direct conv (used only if d_ws is too small)
// ---------------------------------------------------------------------------
__global__ __launch_bounds__(256) void conv_naive(const float* __restrict__ x,
                                                  const float* __restrict__ wgt,
                                                  const float* __restrict__ bias,
                                                  float* __restrict__ out) {
  const size_t idx = (size_t)blockIdx.x * 256 + threadIdx.x;
  if (idx >= (size_t)16 * 256 * 62 * 62) return;
  const int ow = (int)(idx % 62);
  size_t r = idx / 62;
  const int oh = (int)(r % 62); r /= 62;
  const int co = (int)(r % 256);
  const int b = (int)(r / 256);
  float s = bias[co];
  for (int ci = 0; ci < 256; ++ci) {
    const float* xp = x + ((size_t)(b * 256 + ci) * 64 + oh) * 64 + ow;
    const float* wp = wgt + (size_t)(co * 256 + ci) * 9;
#pragma unroll
    for (int kh = 0; kh < 3; ++kh)
#pragma unroll
      for (int kw = 0; kw < 3; ++kw)
        s += xp[kh * 64 + kw] * wp[kh * 3 + kw];
  }
  out[idx] = s;
}

extern "C" void kernel_launch(void* const* d_in, const int* in_sizes, int n_in,
                              void* d_out, int out_size, void* d_ws, size_t ws_size,
                              hipStream_t stream) {
  const float* x = (const float*)d_in[0];
  const float* wgt = (const float*)d_in[1];
  const float* bias = (const float*)d_in[2];
  float* out = (float*)d_out;

  const size_t xt_elems = (size_t)16 * 64 * 64 * 256;       // 16.78M bf16 = 32 MiB
  const size_t wr_elems = (size_t)9 * 256 * 256;            // 1.125 MiB bf16
  const size_t need = (xt_elems + wr_elems) * sizeof(unsigned short);

  if (ws_size < need) {
    // safety fallback: correct but slow
    conv_naive<<<61504, 256, 0, stream>>>(x, wgt, bias, out);
    return;
  }

  unsigned short* xt = (unsigned short*)d_ws;
  unsigned short* wrp = xt + xt_elems;

  xpose_kernel<<<4096, 256, 0, stream>>>(x, xt);
  wpack_kernel<<<2304, 256, 0, stream>>>(wgt, wrp);
  conv_mfma<<<992, 256, 0, stream>>>(xt, wrp, bias, out);
}

// Round 3
// 101.177 us; speedup vs baseline: 1.3898x; 1.3898x over previous
//
#include <hip/hip_runtime.h>
#include <stdint.h>

typedef short short8 __attribute__((ext_vector_type(8)));
typedef float f32x4 __attribute__((ext_vector_type(4)));

#define AS1 __attribute__((address_space(1)))
#define AS3 __attribute__((address_space(3)))

__device__ __forceinline__ void gl_lds16(const void* g, void* l) {
  __builtin_amdgcn_global_load_lds((const AS1 unsigned int*)g,
                                   (AS3 unsigned int*)l, 16, 0, 0);
}

__device__ __forceinline__ unsigned short f2bf(float f) {
  union { float f; unsigned int u; } v; v.f = f;
  return (unsigned short)((v.u + (((v.u >> 16) & 1u) + 0x7fffu)) >> 16);
}

// ---------------------------------------------------------------------------
// Pre-pass 1: x [16][256][64][64] fp32 NCHW -> x_t [16][64][64][256] bf16 NHWC
// ---------------------------------------------------------------------------
__global__ __launch_bounds__(256) void xpose_kernel(const float* __restrict__ x,
                                                    unsigned short* __restrict__ xt) {
  __shared__ float tile[64][68];
  const int bid = blockIdx.x;
  const int cchunk = bid & 3;
  const int y = (bid >> 2) & 63;
  const int b = bid >> 8;
  const int t = threadIdx.x;
  const int ci0 = cchunk * 64;

  const int cc = t >> 2;
  const int xo = (t & 3) * 16;
  const float* src = x + (((size_t)(b * 256 + ci0 + cc) * 64 + y) * 64 + xo);
  float4 v0 = ((const float4*)src)[0];
  float4 v1 = ((const float4*)src)[1];
  float4 v2 = ((const float4*)src)[2];
  float4 v3 = ((const float4*)src)[3];
  *(float4*)&tile[cc][xo + 0]  = v0;
  *(float4*)&tile[cc][xo + 4]  = v1;
  *(float4*)&tile[cc][xo + 8]  = v2;
  *(float4*)&tile[cc][xo + 12] = v3;
  __syncthreads();

  const int xpos = t >> 2;
  const int ccg = (t & 3) * 16;
  unsigned int pk[8];
#pragma unroll
  for (int e = 0; e < 8; ++e) {
    unsigned int lo = f2bf(tile[ccg + 2 * e][xpos]);
    unsigned int hi = f2bf(tile[ccg + 2 * e + 1][xpos]);
    pk[e] = lo | (hi << 16);
  }
  unsigned short* dst = xt + ((size_t)(b * 4096 + y * 64 + xpos) * 256 + ci0 + ccg);
  uint4 w0; w0.x = pk[0]; w0.y = pk[1]; w0.z = pk[2]; w0.w = pk[3];
  uint4 w1; w1.x = pk[4]; w1.y = pk[5]; w1.z = pk[6]; w1.w = pk[7];
  ((uint4*)dst)[0] = w0;
  ((uint4*)dst)[1] = w1;
}

// ---------------------------------------------------------------------------
// Pre-pass 2: w [256co][256ci][3][3] fp32 -> w_r [9 tap][256co][256ci] bf16
// ---------------------------------------------------------------------------
__global__ __launch_bounds__(256) void wpack_kernel(const float* __restrict__ w,
                                                    unsigned short* __restrict__ wrp) {
  const int idx = blockIdx.x * 256 + threadIdx.x;
  const int ci = idx & 255;
  const int co = (idx >> 8) & 255;
  const int p = idx >> 16;
  wrp[idx] = f2bf(w[(size_t)(co * 256 + ci) * 9 + p]);
}

// ---------------------------------------------------------------------------
// Main: implicit-GEMM conv, 256co x 256px tile, 8 waves (4co x 2px),
// 4-deep LDS ring + counted vmcnt + T2 swizzle + T5 setprio.
// 72 K-tiles of BK=32 (9 taps x 8 ci-chunks), 2 phases per K-tile.
// ---------------------------------------------------------------------------
__global__ __launch_bounds__(512, 2) void conv_mfma8(
    const unsigned short* __restrict__ xt,
    const unsigned short* __restrict__ wrp,
    const float* __restrict__ bias,
    float* __restrict__ out) {
  __shared__ unsigned short lds[4 * 16384];  // 4 bufs x (A 8192 + B 8192) ushorts = 128 KiB

  const int tid = threadIdx.x;
  const int lane = tid & 63;
  const int wv = tid >> 6;
  const int wr = wv >> 2;        // px half (0..1)
  const int wc = wv & 3;         // co quarter (0..3)
  const int bid = blockIdx.x;    // 256 = 16 images x 16 row-tiles
  const int b = bid >> 4;
  const int oh0 = (bid & 15) * 4;

  // ---- staging statics (rule 21: linear LDS dest, inverse-swizzled global src) ----
  const int srow = tid >> 2;                  // 0..127
  const int sslot = tid & 3;
  const int sl = sslot ^ ((srow >> 1) & 3);   // same involution on src and read
  const unsigned short* gA0 = wrp + (size_t)srow * 256 + sl * 8;
  const unsigned short* gA1 = wrp + (size_t)(128 + srow) * 256 + sl * 8;
  const unsigned short* gB[2];
#pragma unroll
  for (int i = 0; i < 2; ++i) {
    const int px = i * 128 + srow;
    const int prow = px >> 6, pcol = px & 63;
    const int y = min(oh0 + prow, 61);        // clamp pad rows in-bounds
    const int xc = min(pcol, 61);             // clamp pad cols in-bounds
    gB[i] = xt + ((size_t)(b * 64 + y) * 64 + xc) * 256 + sl * 8;
  }
  const unsigned ldsA0 = wv * 512;            // ushort offsets within buf
  const unsigned ldsA1 = 4096 + wv * 512;
  const unsigned ldsB0 = 8192 + wv * 512;
  const unsigned ldsB1 = 12288 + wv * 512;

  // ---- fragment read offsets (swizzled, ushorts within buf) ----
  int aoff[4], boff[8];
#pragma unroll
  for (int m = 0; m < 4; ++m) {
    const int row = wc * 64 + m * 16 + (lane & 15);
    const int s = (lane >> 4) ^ ((row >> 1) & 3);
    aoff[m] = row * 32 + s * 8;
  }
#pragma unroll
  for (int n = 0; n < 8; ++n) {
    const int row = wr * 128 + n * 16 + (lane & 15);
    const int s = (lane >> 4) ^ ((row >> 1) & 3);
    boff[n] = 8192 + row * 32 + s * 8;
  }

  auto stageA = [&](int kt) {
    const int tap = kt >> 3, chunk = (kt & 7) * 32;
    const int Aoff = tap * 65536 + chunk;
    unsigned short* base = lds + (kt & 3) * 16384;
    gl_lds16(gA0 + Aoff, base + ldsA0);
    gl_lds16(gA1 + Aoff, base + ldsA1);
  };
  auto stageB = [&](int kt) {
    const int tap = kt >> 3, chunk = (kt & 7) * 32;
    const int kh = (tap * 11) >> 5, kw = tap - kh * 3;
    const int Boff = (kh * 64 + kw) * 256 + chunk;
    unsigned short* base = lds + (kt & 3) * 16384;
    gl_lds16(gB[0] + Boff, base + ldsB0);
    gl_lds16(gB[1] + Boff, base + ldsB1);
  };

  f32x4 acc[4][8] = {};

  // prologue: 3 K-tiles in flight, drain tile 0
  stageA(0); stageB(0);
  stageA(1); stageB(1);
  stageA(2); stageB(2);
  asm volatile("s_waitcnt vmcnt(8)" ::: "memory");
  __builtin_amdgcn_s_barrier();

  for (int kt = 0; kt < 72; ++kt) {
    unsigned short* buf = lds + (kt & 3) * 16384;
    // ---------- phase A: A frags + B quadrants 0-3 ----------
    short8 a[4], bq[4];
#pragma unroll
    for (int m = 0; m < 4; ++m) a[m] = *(const short8*)(buf + aoff[m]);
#pragma unroll
    for (int n = 0; n < 4; ++n) bq[n] = *(const short8*)(buf + boff[n]);
    if (kt < 69) stageA(kt + 3);
    __builtin_amdgcn_s_barrier();
    asm volatile("s_waitcnt lgkmcnt(0)" ::: "memory");
    __builtin_amdgcn_sched_barrier(0);
    __builtin_amdgcn_s_setprio(1);
#pragma unroll
    for (int m = 0; m < 4; ++m)
#pragma unroll
      for (int n = 0; n < 4; ++n)
        acc[m][n] = __builtin_amdgcn_mfma_f32_16x16x32_bf16(a[m], bq[n], acc[m][n], 0, 0, 0);
    __builtin_amdgcn_s_setprio(0);
    __builtin_amdgcn_s_barrier();
    // ---------- phase B: B quadrants 4-7 ----------
#pragma unroll
    for (int n = 0; n < 4; ++n) bq[n] = *(const short8*)(buf + boff[4 + n]);
    if (kt < 69) stageB(kt + 3);
    __builtin_amdgcn_s_barrier();
    asm volatile("s_waitcnt lgkmcnt(0)" ::: "memory");
    __builtin_amdgcn_sched_barrier(0);
    __builtin_amdgcn_s_setprio(1);
#pragma unroll
    for (int m = 0; m < 4; ++m)
#pragma unroll
      for (int n = 0; n < 4; ++n)
        acc[m][4 + n] = __builtin_amdgcn_mfma_f32_16x16x32_bf16(a[m], bq[n], acc[m][4 + n], 0, 0, 0);
    __builtin_amdgcn_s_setprio(0);
    // counted drain: guarantee tile kt+1 landed after the barrier (never vmcnt(0) mid-loop)
    if (kt <= 68)      asm volatile("s_waitcnt vmcnt(8)" ::: "memory");
    else if (kt == 69) asm volatile("s_waitcnt vmcnt(4)" ::: "memory");
    else if (kt == 70) asm volatile("s_waitcnt vmcnt(0)" ::: "memory");
    __builtin_amdgcn_s_barrier();
  }

  // ---- epilogue: D col=lane&15 -> px, row=(lane>>4)*4+j -> co ----
  const int rb = (lane >> 4) * 4;
  const int colp = lane & 15;
  float bv[4][4];
#pragma unroll
  for (int m = 0; m < 4; ++m)
#pragma unroll
    for (int j = 0; j < 4; ++j)
      bv[m][j] = bias[wc * 64 + m * 16 + rb + j];
#pragma unroll
  for (int m = 0; m < 4; ++m) {
#pragma unroll
    for (int n = 0; n < 8; ++n) {
      const int px = wr * 128 + n * 16 + colp;
      const int prow = px >> 6, ow = px & 63;
      const int oh = oh0 + prow;
      if (ow < 62 && oh < 62) {
#pragma unroll
        for (int j = 0; j < 4; ++j) {
          const int co = wc * 64 + m * 16 + rb + j;
          out[((size_t)(b * 256 + co) * 62 + oh) * 62 + ow] = acc[m][n][j] + bv[m][j];
        }
      }
    }
  }
}

// ---------------------------------------------------------------------------
// Fallback: naive fp32 direct conv (used only if d_ws is too small)
// ---------------------------------------------------------------------------
__global__ __launch_bounds__(256) void conv_naive(const float* __restrict__ x,
                                                  const float* __restrict__ wgt,
                                                  const float* __restrict__ bias,
                                                  float* __restrict__ out) {
  const size_t idx = (size_t)blockIdx.x * 256 + threadIdx.x;
  if (idx >= (size_t)16 * 256 * 62 * 62) return;
  const int ow = (int)(idx % 62);
  size_t r = idx / 62;
  const int oh = (int)(r % 62); r /= 62;
  const int co = (int)(r % 256);
  const int b = (int)(r / 256);
  float s = bias[co];
  for (int ci = 0; ci < 256; ++ci) {
    const float* xp = x + ((size_t)(b * 256 + ci) * 64 + oh) * 64 + ow;
    const float* wp = wgt + (size_t)(co * 256 + ci) * 9;
#pragma unroll
    for (int kh = 0; kh < 3; ++kh)
#pragma unroll
      for (int kw = 0; kw < 3; ++kw)
        s += xp[kh * 64 + kw] * wp[kh * 3 + kw];
  }
  out[idx] = s;
}

extern "C" void kernel_launch(void* const* d_in, const int* in_sizes, int n_in,
                              void* d_out, int out_size, void* d_ws, size_t ws_size,
                              hipStream_t stream) {
  const float* x = (const float*)d_in[0];
  const float* wgt = (const float*)d_in[1];
  const float* bias = (const float*)d_in[2];
  float* out = (float*)d_out;

  const size_t xt_elems = (size_t)16 * 64 * 64 * 256;
  const size_t wr_elems = (size_t)9 * 256 * 256;
  const size_t need = (xt_elems + wr_elems) * sizeof(unsigned short);

  if (ws_size < need) {
    conv_naive<<<61504, 256, 0, stream>>>(x, wgt, bias, out);
    return;
  }

  unsigned short* xt = (unsigned short*)d_ws;
  unsigned short* wrp = xt + xt_elems;

  xpose_kernel<<<4096, 256, 0, stream>>>(x, xt);
  wpack_kernel<<<2304, 256, 0, stream>>>(wgt, wrp);
  conv_mfma8<<<256, 512, 0, stream>>>(xt, wrp, bias, out);
}